// Round 5
// baseline (1884.745 us; speedup 1.0000x reference)
//
#include <hip/hip_runtime.h>
#include <cstddef>

#define BB   256   // batch
#define UU   8     // in_units
#define ISZ  1152  // in_size
#define JJ   10    // out_units
#define DD   16    // out_size
#define JD   (JJ*DD)        // 160
#define ICH  9              // i per s block
#define NCH  (ISZ/ICH)      // 128
#define ICA  2              // i per agreement block
#define NCA  (ISZ/ICA)      // 576
#define WROW (JJ*DD*UU)     // 1280 floats per i row of W

// Runtime zero in a VGPR the compiler can't see through: forces W addresses
// onto the VECTOR memory path (global_load_dwordx4, deep vmcnt queue) instead
// of s_load (scalar pipe, ~2 outstanding misses -> latency-serialized).
__device__ __forceinline__ int vzero() {
    int z;
    asm volatile("v_mov_b32 %0, 0" : "=v"(z));
    return z;
}

// ---------------- transpose: x[b,u,i] -> x2[i][b][u]; also init b_ij=1 ----------------
__global__ void transpose_x(const float* __restrict__ x, float* __restrict__ x2,
                            float* __restrict__ b_ij) {
    __shared__ float buf[32][8][65];   // [b_local][u][i_local(+pad)]
    int it = blockIdx.x;               // 18 tiles of 64 i
    int bt = blockIdx.y;               // 8 tiles of 32 b
    int i0 = it * 64, b0 = bt * 32;
    int t = threadIdx.x;
    int lane = t & 63, wv = t >> 6;

    int flat = blockIdx.y * 18 + blockIdx.x;
    if (flat < 45) b_ij[flat * 256 + t] = 1.0f;     // 45*256 = 11520

    for (int rep = 0; rep < 64; ++rep) {
        int row = rep * 4 + wv;        // 0..255
        int bl = row >> 3, u = row & 7;
        buf[bl][u][lane] = x[(size_t)(b0 + bl) * (UU * ISZ) + (size_t)u * ISZ + i0 + lane];
    }
    __syncthreads();
    int bl = t >> 3, u = t & 7;
    for (int il = 0; il < 64; ++il) {
        x2[((size_t)(i0 + il) * BB + b0 + bl) * UU + u] = buf[bl][u][il];
    }
}

// ---------------- s step, register-blocked, fused softmax ----------------
// grid (NCH, 2 j-halves, 2 d-halves), block 256 = all b. 9 i x 5 j x 8 d per block.
// W loads: wave-uniform address held in VGPR -> vector loads, MLP-hidden.
__global__ __launch_bounds__(256, 2) void s_kernel(
        const float* __restrict__ x2, const float* __restrict__ W,
        const float* __restrict__ b_ij, float* __restrict__ s_part, int first) {
    int ic = blockIdx.x, jh = blockIdx.y, dh = blockIdx.z;
    int j0 = jh * 5, d0 = dh * 8, i0 = ic * ICH;
    int t = threadIdx.x;
    int lane = t & 63, wv = t >> 6;
    __shared__ float c_lds[5][ICH];
    __shared__ float minv[5][2];

    if (first) {
        if (t < 5 * ICH) c_lds[t / ICH][t % ICH] = 1.0f / 1152.0f;  // softmax(ones)
    } else {
        for (int jj = wv; jj < 5; jj += 4) {
            const float* bp = b_ij + (size_t)(j0 + jj) * ISZ;
            float m = -1e30f;
            for (int k = lane; k < ISZ; k += 64) m = fmaxf(m, bp[k]);
#pragma unroll
            for (int off = 32; off; off >>= 1) m = fmaxf(m, __shfl_down(m, off, 64));
            m = __shfl(m, 0, 64);
            float s = 0.f;
            for (int k = lane; k < ISZ; k += 64) s += __expf(bp[k] - m);
#pragma unroll
            for (int off = 32; off; off >>= 1) s += __shfl_down(s, off, 64);
            if (lane == 0) { minv[jj][0] = m; minv[jj][1] = 1.f / s; }
        }
        __syncthreads();
        if (t < 5 * ICH) {
            int jj = t / ICH, ii = t % ICH;
            c_lds[jj][ii] = __expf(b_ij[(size_t)(j0 + jj) * ISZ + i0 + ii] - minv[jj][0]) * minv[jj][1];
        }
    }
    __syncthreads();

    int vz = vzero();
    int b = t;
    float4 xa[ICH], xb[ICH];
#pragma unroll
    for (int ii = 0; ii < ICH; ++ii) {
        const float4* p = (const float4*)(x2 + ((size_t)(i0 + ii) * BB + b) * UU);
        xa[ii] = p[0]; xb[ii] = p[1];
    }
    float acc[5][8];
#pragma unroll
    for (int jj = 0; jj < 5; ++jj)
#pragma unroll
        for (int dd = 0; dd < 8; ++dd) acc[jj][dd] = 0.f;

#pragma unroll
    for (int jj = 0; jj < 5; ++jj) {
#pragma unroll
        for (int ii = 0; ii < ICH; ++ii) {
            const float4* Wp = (const float4*)(W + (size_t)(i0 + ii) * WROW
                                               + (j0 + jj) * (DD * UU) + d0 * UU) + vz;
            float ci = c_lds[jj][ii];
            // two chunks of 4 d's: 8 float4 W regs in flight per chunk
#pragma unroll
            for (int half = 0; half < 2; ++half) {
                float4 w[8];
#pragma unroll
                for (int q = 0; q < 8; ++q) w[q] = Wp[half * 8 + q];
#pragma unroll
                for (int k = 0; k < 4; ++k) {
                    int dd = half * 4 + k;
                    float s = w[k*2].x * xa[ii].x + w[k*2].y * xa[ii].y
                            + w[k*2].z * xa[ii].z + w[k*2].w * xa[ii].w
                            + w[k*2+1].x * xb[ii].x + w[k*2+1].y * xb[ii].y
                            + w[k*2+1].z * xb[ii].z + w[k*2+1].w * xb[ii].w;
                    acc[jj][dd] += ci * s;
                }
            }
        }
    }
#pragma unroll
    for (int jj = 0; jj < 5; ++jj) {
        float* sp = s_part + ((size_t)ic * BB + b) * JD + (j0 + jj) * DD + d0;
        ((float4*)sp)[0] = make_float4(acc[jj][0], acc[jj][1], acc[jj][2], acc[jj][3]);
        ((float4*)sp)[1] = make_float4(acc[jj][4], acc[jj][5], acc[jj][6], acc[jj][7]);
    }
}

// ---------------- reduce partials + squash; v[b][jd] and vT[jd][b] ----------------
__global__ void reduce_squash_kernel(const float* __restrict__ s_part,
                                     float* __restrict__ v, float* __restrict__ vT) {
    int b = blockIdx.x;
    int t = threadIdx.x;   // 192 threads, t<160 active
    __shared__ float sm[JD];
    float s = 0.f;
    if (t < JD) {
#pragma unroll 8
        for (int ic = 0; ic < NCH; ++ic) s += s_part[((size_t)ic * BB + b) * JD + t];
        sm[t] = s;
    }
    __syncthreads();
    if (t < JD) {
        int d = t & 15;
        float msq = 0.f;
#pragma unroll
        for (int j = 0; j < JJ; ++j) { float x = sm[j * DD + d]; msq += x * x; }
        float val = msq / (1.f + msq) * s * rsqrtf(msq);
        v[(size_t)b * JD + t] = val;
        vT[(size_t)t * BB + b] = val;
    }
}

// ---------------- agreement: b_ij[j][i] += (1/B) sum_{b,d} u_hat*v ----------------
// grid (NCA, 2 j-halves), block 256 = all b. 2 i x 5 j per block; W via vector loads.
__global__ __launch_bounds__(256, 2) void agreement_kernel(
        const float* __restrict__ x2, const float* __restrict__ W,
        const float* __restrict__ vT, float* __restrict__ b_ij) {
    int ic = blockIdx.x, jh = blockIdx.y;
    int j0 = jh * 5, i0 = ic * ICA;
    int b = threadIdx.x;
    int lane = b & 63, wv = b >> 6;
    int vz = vzero();

    float vv[5][16];
#pragma unroll
    for (int jj = 0; jj < 5; ++jj)
#pragma unroll
        for (int dd = 0; dd < 16; ++dd)
            vv[jj][dd] = vT[(size_t)((j0 + jj) * DD + dd) * BB + b];   // coalesced

    float4 xa[ICA], xb[ICA];
#pragma unroll
    for (int ii = 0; ii < ICA; ++ii) {
        const float4* p = (const float4*)(x2 + ((size_t)(i0 + ii) * BB + b) * UU);
        xa[ii] = p[0]; xb[ii] = p[1];
    }

    float acc[5][ICA];
#pragma unroll
    for (int jj = 0; jj < 5; ++jj) {
#pragma unroll
        for (int ii = 0; ii < ICA; ++ii) {
            const float4* Wp = (const float4*)(W + (size_t)(i0 + ii) * WROW
                                               + (j0 + jj) * (DD * UU)) + vz;
            float sum = 0.f;
#pragma unroll
            for (int dq = 0; dq < 4; ++dq) {       // 4 d's per chunk
                float4 w[8];
#pragma unroll
                for (int q = 0; q < 8; ++q) w[q] = Wp[dq * 8 + q];
#pragma unroll
                for (int k = 0; k < 4; ++k) {
                    int dd = dq * 4 + k;
                    float s = w[k*2].x * xa[ii].x + w[k*2].y * xa[ii].y
                            + w[k*2].z * xa[ii].z + w[k*2].w * xa[ii].w
                            + w[k*2+1].x * xb[ii].x + w[k*2+1].y * xb[ii].y
                            + w[k*2+1].z * xb[ii].z + w[k*2+1].w * xb[ii].w;
                    sum += s * vv[jj][dd];
                }
            }
            acc[jj][ii] = sum;
        }
    }

    __shared__ float red[4][5][ICA];
#pragma unroll
    for (int jj = 0; jj < 5; ++jj)
#pragma unroll
        for (int ii = 0; ii < ICA; ++ii) {
            float a = acc[jj][ii];
#pragma unroll
            for (int off = 32; off; off >>= 1) a += __shfl_down(a, off, 64);
            if (lane == 0) red[wv][jj][ii] = a;
        }
    __syncthreads();
    if (b < 5 * ICA) {
        int jj = b / ICA, ii = b % ICA;
        float r = red[0][jj][ii] + red[1][jj][ii] + red[2][jj][ii] + red[3][jj][ii];
        b_ij[(size_t)(j0 + jj) * ISZ + i0 + ii] += r * (1.0f / (float)BB);
    }
}

extern "C" void kernel_launch(void* const* d_in, const int* in_sizes, int n_in,
                              void* d_out, int out_size, void* d_ws, size_t ws_size,
                              hipStream_t stream) {
    const float* x = (const float*)d_in[0];   // (256, 8, 1152)
    const float* W = (const float*)d_in[1];   // (1, 1152, 10, 16, 8)
    float* out = (float*)d_out;               // (256, 10, 16, 1) -> v

    float* x2     = (float*)d_ws;                   // 1152*256*8 = 2,359,296 floats
    float* b_ij   = x2 + (size_t)ISZ * BB * UU;     // 11,520
    float* vT     = b_ij + ISZ * JJ;                // 40,960
    float* s_part = vT + JD * BB;                   // 128*256*160 = 5,242,880 floats
    float* v      = out;

    hipLaunchKernelGGL(transpose_x, dim3(18, 8), dim3(256), 0, stream, x, x2, b_ij);

    for (int it = 0; it < 3; ++it) {
        hipLaunchKernelGGL(s_kernel, dim3(NCH, 2, 2), dim3(256), 0, stream,
                           x2, W, b_ij, s_part, it == 0 ? 1 : 0);
        hipLaunchKernelGGL(reduce_squash_kernel, dim3(BB), dim3(192), 0, stream,
                           s_part, v, vT);
        if (it < 2) {
            hipLaunchKernelGGL(agreement_kernel, dim3(NCA, 2), dim3(256), 0, stream,
                               x2, W, vT, b_ij);
        }
    }
}

// Round 6
// 836.854 us; speedup vs baseline: 2.2522x; 2.2522x over previous
//
#include <hip/hip_runtime.h>
#include <cstddef>

#define BB   256   // batch
#define UU   8     // in_units
#define ISZ  1152  // in_size
#define JJ   10    // out_units
#define DD   16    // out_size
#define JD   (JJ*DD)        // 160
#define ICH  4              // i per block (s and agreement)
#define NIC  (ISZ/ICH)      // 288
#define JT   2              // j per block
#define NJH  (JJ/JT)        // 5

// ---------------- transpose: x[b,u,i] -> x2[i][b][u]; also init b_ij=1 ----------------
__global__ void transpose_x(const float* __restrict__ x, float* __restrict__ x2,
                            float* __restrict__ b_ij) {
    __shared__ float buf[32][8][65];   // [b_local][u][i_local(+pad)]
    int it = blockIdx.x;               // 18 tiles of 64 i
    int bt = blockIdx.y;               // 8 tiles of 32 b
    int i0 = it * 64, b0 = bt * 32;
    int t = threadIdx.x;
    int lane = t & 63, wv = t >> 6;

    int flat = blockIdx.y * 18 + blockIdx.x;
    if (flat < 45) b_ij[flat * 256 + t] = 1.0f;     // 45*256 = 11520

    for (int rep = 0; rep < 64; ++rep) {
        int row = rep * 4 + wv;        // 0..255
        int bl = row >> 3, u = row & 7;
        buf[bl][u][lane] = x[(size_t)(b0 + bl) * (UU * ISZ) + (size_t)u * ISZ + i0 + lane];
    }
    __syncthreads();
    int bl = t >> 3, u = t & 7;
    for (int il = 0; il < 64; ++il) {
        x2[((size_t)(i0 + il) * BB + b0 + bl) * UU + u] = buf[bl][u][il];
    }
}

// ---------------- s step: LDS-staged W, 2 b per thread, fused softmax ----------------
// grid (NIC, NJH), block 256: t = dh*128 + bp; thread handles b = 2bp, 2bp+1 and 8 d.
__global__ __launch_bounds__(256, 3) void s_kernel(
        const float* __restrict__ x2, const float* __restrict__ W,
        const float* __restrict__ b_ij, float* __restrict__ s_part, int first) {
    int ic = blockIdx.x, jh = blockIdx.y;
    int i0 = ic * ICH, j0 = jh * JT;
    int t = threadIdx.x;
    int bp = t & 127, dh = t >> 7;
    int lane = t & 63, wv = t >> 6;

    __shared__ float4 wlds4[ICH * 64];   // [ii][ (jj,d,u) flattened /4 ] = 4KB
    __shared__ float c_lds[JT][ICH];
    __shared__ float minv[JT][2];

    // stage W tile (coalesced, per-lane distinct addresses -> vector path)
    {
        int ii = t >> 6, rem = t & 63;
        const float4* W4 = (const float4*)W;
        wlds4[t] = W4[(size_t)(i0 + ii) * 320 + j0 * 32 + rem];
    }
    // softmax over i for this block's 2 j (waves 0,1; one j each)
    if (!first && wv < JT) {
        int jj = wv;
        const float* bpr = b_ij + (size_t)(j0 + jj) * ISZ;
        float m = -1e30f;
        for (int k = lane; k < ISZ; k += 64) m = fmaxf(m, bpr[k]);
#pragma unroll
        for (int off = 32; off; off >>= 1) m = fmaxf(m, __shfl_down(m, off, 64));
        m = __shfl(m, 0, 64);
        float ss = 0.f;
        for (int k = lane; k < ISZ; k += 64) ss += __expf(bpr[k] - m);
#pragma unroll
        for (int off = 32; off; off >>= 1) ss += __shfl_down(ss, off, 64);
        if (lane == 0) { minv[jj][0] = m; minv[jj][1] = 1.f / ss; }
    }
    __syncthreads();
    if (t < JT * ICH) {
        int jj = t >> 2, ii = t & 3;
        c_lds[jj][ii] = first ? (1.0f / 1152.0f)
            : __expf(b_ij[(size_t)(j0 + jj) * ISZ + i0 + ii] - minv[jj][0]) * minv[jj][1];
    }
    __syncthreads();

    int b0 = bp * 2;
    float acc0[JT][8], acc1[JT][8];
#pragma unroll
    for (int jj = 0; jj < JT; ++jj)
#pragma unroll
        for (int dd = 0; dd < 8; ++dd) { acc0[jj][dd] = 0.f; acc1[jj][dd] = 0.f; }

#pragma unroll
    for (int ii = 0; ii < ICH; ++ii) {
        const float4* xp = (const float4*)(x2 + ((size_t)(i0 + ii) * BB + b0) * UU);
        float4 xa0 = xp[0], xb0 = xp[1], xa1 = xp[2], xb1 = xp[3];
#pragma unroll
        for (int jj = 0; jj < JT; ++jj) {
            float ci = c_lds[jj][ii];
            float4 ca0 = make_float4(xa0.x*ci, xa0.y*ci, xa0.z*ci, xa0.w*ci);
            float4 cb0 = make_float4(xb0.x*ci, xb0.y*ci, xb0.z*ci, xb0.w*ci);
            float4 ca1 = make_float4(xa1.x*ci, xa1.y*ci, xa1.z*ci, xa1.w*ci);
            float4 cb1 = make_float4(xb1.x*ci, xb1.y*ci, xb1.z*ci, xb1.w*ci);
#pragma unroll
            for (int dd = 0; dd < 8; ++dd) {
                int wi = ii * 64 + (jj * 16 + dh * 8 + dd) * 2;
                float4 w0 = wlds4[wi];      // broadcast LDS read (same addr all lanes)
                float4 w1 = wlds4[wi + 1];
                acc0[jj][dd] += w0.x*ca0.x + w0.y*ca0.y + w0.z*ca0.z + w0.w*ca0.w
                              + w1.x*cb0.x + w1.y*cb0.y + w1.z*cb0.z + w1.w*cb0.w;
                acc1[jj][dd] += w0.x*ca1.x + w0.y*ca1.y + w0.z*ca1.z + w0.w*ca1.w
                              + w1.x*cb1.x + w1.y*cb1.y + w1.z*cb1.z + w1.w*cb1.w;
            }
        }
    }
#pragma unroll
    for (int jj = 0; jj < JT; ++jj) {
        size_t base0 = ((size_t)ic * BB + b0) * JD + (j0 + jj) * DD + dh * 8;
        ((float4*)(s_part + base0))[0] = make_float4(acc0[jj][0], acc0[jj][1], acc0[jj][2], acc0[jj][3]);
        ((float4*)(s_part + base0))[1] = make_float4(acc0[jj][4], acc0[jj][5], acc0[jj][6], acc0[jj][7]);
        size_t base1 = base0 + JD;
        ((float4*)(s_part + base1))[0] = make_float4(acc1[jj][0], acc1[jj][1], acc1[jj][2], acc1[jj][3]);
        ((float4*)(s_part + base1))[1] = make_float4(acc1[jj][4], acc1[jj][5], acc1[jj][6], acc1[jj][7]);
    }
}

// ---------------- reduce partials + squash; v[b][jd] and vT[jd][b] ----------------
__global__ void reduce_squash_kernel(const float* __restrict__ s_part,
                                     float* __restrict__ v, float* __restrict__ vT) {
    int b = blockIdx.x;
    int t = threadIdx.x;   // 192 threads, t<160 active
    __shared__ float sm[JD];
    float s = 0.f;
    if (t < JD) {
        size_t base = (size_t)b * JD + t;
#pragma unroll 8
        for (int ic = 0; ic < NIC; ++ic) s += s_part[base + (size_t)ic * BB * JD];
        sm[t] = s;
    }
    __syncthreads();
    if (t < JD) {
        int d = t & 15;
        float msq = 0.f;
#pragma unroll
        for (int j = 0; j < JJ; ++j) { float x = sm[j * DD + d]; msq += x * x; }
        float val = msq / (1.f + msq) * s * rsqrtf(msq);
        v[(size_t)b * JD + t] = val;
        vT[(size_t)t * BB + b] = val;
    }
}

// ---------------- agreement: b_ij[j][i] += (1/B) sum_{b,d} u_hat*v ----------------
// grid (NIC, NJH), block 256: same LDS-staged W, 2 b per thread, 8 d per thread.
__global__ __launch_bounds__(256, 3) void agreement_kernel(
        const float* __restrict__ x2, const float* __restrict__ W,
        const float* __restrict__ vT, float* __restrict__ b_ij) {
    int ic = blockIdx.x, jh = blockIdx.y;
    int i0 = ic * ICH, j0 = jh * JT;
    int t = threadIdx.x;
    int bp = t & 127, dh = t >> 7;
    int lane = t & 63, wv = t >> 6;

    __shared__ float4 wlds4[ICH * 64];
    __shared__ float red[4][JT][ICH];

    {
        int ii = t >> 6, rem = t & 63;
        const float4* W4 = (const float4*)W;
        wlds4[t] = W4[(size_t)(i0 + ii) * 320 + j0 * 32 + rem];
    }
    // v for this thread's 2 b and 8 d: coalesced float2 reads
    float2 vv[JT][8];
    const float2* vT2 = (const float2*)vT;
#pragma unroll
    for (int jj = 0; jj < JT; ++jj)
#pragma unroll
        for (int dd = 0; dd < 8; ++dd)
            vv[jj][dd] = vT2[(size_t)((j0 + jj) * DD + dh * 8 + dd) * 128 + bp];
    __syncthreads();

    int b0 = bp * 2;
    float acc[JT][ICH];
#pragma unroll
    for (int jj = 0; jj < JT; ++jj)
#pragma unroll
        for (int ii = 0; ii < ICH; ++ii) acc[jj][ii] = 0.f;

#pragma unroll
    for (int ii = 0; ii < ICH; ++ii) {
        const float4* xp = (const float4*)(x2 + ((size_t)(i0 + ii) * BB + b0) * UU);
        float4 xa0 = xp[0], xb0 = xp[1], xa1 = xp[2], xb1 = xp[3];
#pragma unroll
        for (int jj = 0; jj < JT; ++jj) {
#pragma unroll
            for (int dd = 0; dd < 8; ++dd) {
                int wi = ii * 64 + (jj * 16 + dh * 8 + dd) * 2;
                float4 w0 = wlds4[wi];
                float4 w1 = wlds4[wi + 1];
                float d0 = w0.x*xa0.x + w0.y*xa0.y + w0.z*xa0.z + w0.w*xa0.w
                         + w1.x*xb0.x + w1.y*xb0.y + w1.z*xb0.z + w1.w*xb0.w;
                float d1 = w0.x*xa1.x + w0.y*xa1.y + w0.z*xa1.z + w0.w*xa1.w
                         + w1.x*xb1.x + w1.y*xb1.y + w1.z*xb1.z + w1.w*xb1.w;
                acc[jj][ii] += d0 * vv[jj][dd].x + d1 * vv[jj][dd].y;
            }
        }
    }

#pragma unroll
    for (int jj = 0; jj < JT; ++jj)
#pragma unroll
        for (int ii = 0; ii < ICH; ++ii) {
            float a = acc[jj][ii];
#pragma unroll
            for (int off = 32; off; off >>= 1) a += __shfl_down(a, off, 64);
            if (lane == 0) red[wv][jj][ii] = a;
        }
    __syncthreads();
    if (t < JT * ICH) {
        int jj = t >> 2, ii = t & 3;
        float r = red[0][jj][ii] + red[1][jj][ii] + red[2][jj][ii] + red[3][jj][ii];
        b_ij[(size_t)(j0 + jj) * ISZ + i0 + ii] += r * (1.0f / (float)BB);
    }
}

extern "C" void kernel_launch(void* const* d_in, const int* in_sizes, int n_in,
                              void* d_out, int out_size, void* d_ws, size_t ws_size,
                              hipStream_t stream) {
    const float* x = (const float*)d_in[0];   // (256, 8, 1152)
    const float* W = (const float*)d_in[1];   // (1, 1152, 10, 16, 8)
    float* out = (float*)d_out;               // (256, 10, 16, 1) -> v

    float* x2     = (float*)d_ws;                   // 2,359,296 floats
    float* b_ij   = x2 + (size_t)ISZ * BB * UU;     // 11,520
    float* vT     = b_ij + ISZ * JJ;                // 40,960
    float* s_part = vT + JD * BB;                   // 288*256*160 = 11,796,480 floats
    float* v      = out;

    hipLaunchKernelGGL(transpose_x, dim3(18, 8), dim3(256), 0, stream, x, x2, b_ij);

    for (int it = 0; it < 3; ++it) {
        hipLaunchKernelGGL(s_kernel, dim3(NIC, NJH), dim3(256), 0, stream,
                           x2, W, b_ij, s_part, it == 0 ? 1 : 0);
        hipLaunchKernelGGL(reduce_squash_kernel, dim3(BB), dim3(192), 0, stream,
                           s_part, v, vT);
        if (it < 2) {
            hipLaunchKernelGGL(agreement_kernel, dim3(NIC, NJH), dim3(256), 0, stream,
                               x2, W, vT, b_ij);
        }
    }
}

// Round 7
// 237.415 us; speedup vs baseline: 7.9386x; 3.5249x over previous
//
#include <hip/hip_runtime.h>
#include <cstddef>

#define BB   256    // batch (GEMM1 M)
#define UU   8      // in_units
#define ISZ  1152   // in_size
#define JJ   10     // out_units
#define DD   16     // out_size
#define JD   (JJ*DD)      // 160 = GEMM N
#define K1   (UU*ISZ)     // 9216 = GEMM1 K / GEMM2 N
#define KS   16           // split-K factor for sgemm
#define KCH  (K1/KS)      // 576 -> 18 mfma k-steps

typedef short v8s __attribute__((ext_vector_type(8)));   // 8 bf16 in 4 VGPRs
typedef float f4v __attribute__((ext_vector_type(4)));   // mfma accumulator

__device__ __forceinline__ unsigned short f2bf(float f) {
    unsigned int u = __float_as_uint(f);
    unsigned int r = (u + 0x7fffu + ((u >> 16) & 1u)) >> 16;   // RNE
    return (unsigned short)r;
}
__device__ __forceinline__ float bf2f(unsigned short h) {
    return __uint_as_float(((unsigned int)h) << 16);
}

// ---------------- prep: xb16[b][k]=bf16split(x), xT16[k][b], b_ij=1 ----------------
// x is (256, 8, 1152) fp32 = row-major [256][9216] with k=(u,i) already flat.
__global__ void prep_kernel(const float* __restrict__ x,
                            unsigned short* __restrict__ xbh, unsigned short* __restrict__ xbl,
                            unsigned short* __restrict__ xth, unsigned short* __restrict__ xtl,
                            float* __restrict__ b_ij) {
    __shared__ float tile[64][65];
    int kt = blockIdx.x;            // 144 tiles of 64 k
    int bt = blockIdx.y;            // 4 tiles of 64 b
    int k0 = kt * 64, b0 = bt * 64;
    int t = threadIdx.x;
    int lane = t & 63, wv = t >> 6;

    int flat = blockIdx.y * 144 + blockIdx.x;
    if (flat < 45) b_ij[flat * 256 + t] = 1.0f;    // 45*256 = 11520

#pragma unroll
    for (int r = 0; r < 16; ++r) {
        int br = wv * 16 + r;
        float v = x[(size_t)(b0 + br) * K1 + k0 + lane];
        tile[br][lane] = v;
        unsigned short h = f2bf(v);
        size_t o = (size_t)(b0 + br) * K1 + k0 + lane;
        xbh[o] = h;
        xbl[o] = f2bf(v - bf2f(h));
    }
    __syncthreads();
#pragma unroll
    for (int r = 0; r < 16; ++r) {
        int kr = wv * 16 + r;
        float v = tile[lane][kr];
        unsigned short h = f2bf(v);
        size_t o = (size_t)(k0 + kr) * BB + b0 + lane;
        xth[o] = h;
        xtl[o] = f2bf(v - bf2f(h));
    }
}

// ---------------- build B^T with fused softmax ----------------
// grid (160), block 192. BT[(j,d)][k=(u,i)] = bf16split(c[i,j] * W[i,j,d,u]).
__global__ void build_b_kernel(const float* __restrict__ W, const float* __restrict__ b_ij,
                               unsigned short* __restrict__ bth, unsigned short* __restrict__ btl,
                               int first) {
    int jd = blockIdx.x;
    int j = jd >> 4;
    int t = threadIdx.x;            // 192
    int lane = t & 63, wv = t >> 6; // 3 waves
    __shared__ float rm[3], rs[3];

    float m = 0.f, inv = 1.0f / 1152.0f;
    if (!first) {
        const float* bp = b_ij + (size_t)j * ISZ;
        m = -1e30f;
        for (int k = t; k < ISZ; k += 192) m = fmaxf(m, bp[k]);
#pragma unroll
        for (int off = 32; off; off >>= 1) m = fmaxf(m, __shfl_down(m, off, 64));
        if (lane == 0) rm[wv] = m;
        __syncthreads();
        m = fmaxf(fmaxf(rm[0], rm[1]), rm[2]);
        float ss = 0.f;
        for (int k = t; k < ISZ; k += 192) ss += __expf(bp[k] - m);
#pragma unroll
        for (int off = 32; off; off >>= 1) ss += __shfl_down(ss, off, 64);
        if (lane == 0) rs[wv] = ss;
        __syncthreads();
        inv = 1.f / (rs[0] + rs[1] + rs[2]);
    }

    for (int ch = 0; ch < 6; ++ch) {
        int i = ch * 192 + t;
        float ci = first ? inv : __expf(b_ij[(size_t)j * ISZ + i] - m) * inv;
        const float* Wp = W + (size_t)i * (JD * UU) + jd * UU;   // 8 contiguous u
#pragma unroll
        for (int u = 0; u < 8; ++u) {
            float val = ci * Wp[u];
            unsigned short h = f2bf(val);
            size_t o = (size_t)jd * K1 + u * ISZ + i;
            bth[o] = h;
            btl[o] = f2bf(val - bf2f(h));
        }
    }
}

// ---------------- GEMM1 (split-K): s_part[ks][256][160] = x @ B ----------------
// grid (4, 10, KS), block 256 = 4 waves; wave -> mt = bx*4+w, nt = by, ks = bz.
__global__ __launch_bounds__(256) void sgemm_kernel(
        const unsigned short* __restrict__ Ah, const unsigned short* __restrict__ Al,
        const unsigned short* __restrict__ Bh, const unsigned short* __restrict__ Bl,
        float* __restrict__ s_part) {
    int w = threadIdx.x >> 6, lane = threadIdx.x & 63;
    int mt = blockIdx.x * 4 + w;     // 0..15
    int nt = blockIdx.y;             // 0..9
    int ks = blockIdx.z;             // 0..KS-1
    int m0 = mt * 16, n0 = nt * 16;
    int col = lane & 15, q = lane >> 4;

    size_t aoff = (size_t)(m0 + col) * K1 + ks * KCH + q * 8;   // col doubles as m-row
    size_t boff = (size_t)(n0 + col) * K1 + ks * KCH + q * 8;   // B^T row = n
    f4v acc = {0.f, 0.f, 0.f, 0.f};
#pragma unroll
    for (int s = 0; s < KCH / 32; ++s) {
        v8s ah = *(const v8s*)(Ah + aoff);
        v8s al = *(const v8s*)(Al + aoff);
        v8s bh = *(const v8s*)(Bh + boff);
        v8s bl = *(const v8s*)(Bl + boff);
        acc = __builtin_amdgcn_mfma_f32_16x16x32_bf16(ah, bh, acc, 0, 0, 0);
        acc = __builtin_amdgcn_mfma_f32_16x16x32_bf16(ah, bl, acc, 0, 0, 0);
        acc = __builtin_amdgcn_mfma_f32_16x16x32_bf16(al, bh, acc, 0, 0, 0);
        aoff += 32; boff += 32;
    }
    // C/D: col=lane&15 (n), row=q*4+r (m)  [m89-verified]
#pragma unroll
    for (int r = 0; r < 4; ++r)
        s_part[((size_t)ks * BB + m0 + q * 4 + r) * JD + n0 + col] = acc[r];
}

// ---------------- reduce split-K + squash; v -> d_out, vT16 split ----------------
__global__ void reduce_squash_kernel(const float* __restrict__ s_part,
                                     float* __restrict__ v,
                                     unsigned short* __restrict__ vth,
                                     unsigned short* __restrict__ vtl) {
    int b = blockIdx.x;
    int t = threadIdx.x;   // 192, t<160 active
    __shared__ float sm[JD];
    float s = 0.f;
    if (t < JD) {
#pragma unroll
        for (int ks = 0; ks < KS; ++ks) s += s_part[((size_t)ks * BB + b) * JD + t];
        sm[t] = s;
    }
    __syncthreads();
    if (t < JD) {
        int d = t & 15;
        float msq = 0.f;
#pragma unroll
        for (int j = 0; j < JJ; ++j) { float x = sm[j * DD + d]; msq += x * x; }
        float val = msq / (1.f + msq) * s * rsqrtf(msq);
        v[(size_t)b * JD + t] = val;
        unsigned short h = f2bf(val);
        vth[(size_t)t * BB + b] = h;
        vtl[(size_t)t * BB + b] = f2bf(val - bf2f(h));
    }
}

// ---------------- GEMM2: M[160][9216] = vT @ x  (K=256) ----------------
// grid (10, 144), block 256 = 4 waves; wave -> mt = bx, nt = by*4+w.
__global__ __launch_bounds__(256) void mgemm_kernel(
        const unsigned short* __restrict__ Ah, const unsigned short* __restrict__ Al,
        const unsigned short* __restrict__ Bh, const unsigned short* __restrict__ Bl,
        float* __restrict__ M) {
    int w = threadIdx.x >> 6, lane = threadIdx.x & 63;
    int mt = blockIdx.x;               // 0..9
    int nt = blockIdx.y * 4 + w;       // 0..575
    int m0 = mt * 16, n0 = nt * 16;
    int col = lane & 15, q = lane >> 4;

    size_t aoff = (size_t)(m0 + col) * BB + q * 8;   // vT16 [160][256]
    size_t boff = (size_t)(n0 + col) * BB + q * 8;   // xT16 [9216][256] = B^T
    f4v acc = {0.f, 0.f, 0.f, 0.f};
#pragma unroll
    for (int s = 0; s < BB / 32; ++s) {
        v8s ah = *(const v8s*)(Ah + aoff);
        v8s al = *(const v8s*)(Al + aoff);
        v8s bh = *(const v8s*)(Bh + boff);
        v8s bl = *(const v8s*)(Bl + boff);
        acc = __builtin_amdgcn_mfma_f32_16x16x32_bf16(ah, bh, acc, 0, 0, 0);
        acc = __builtin_amdgcn_mfma_f32_16x16x32_bf16(ah, bl, acc, 0, 0, 0);
        acc = __builtin_amdgcn_mfma_f32_16x16x32_bf16(al, bh, acc, 0, 0, 0);
        aoff += 32; boff += 32;
    }
#pragma unroll
    for (int r = 0; r < 4; ++r)
        M[(size_t)(m0 + q * 4 + r) * K1 + n0 + col] = acc[r];
}

// ---------------- agreement epilogue: b_ij[j][i] += (1/B) sum_{d,u} W*M ----------------
// grid (18, 10), block 64: lane = i within chunk.
__global__ void agree_kernel(const float* __restrict__ W, const float* __restrict__ M,
                             float* __restrict__ b_ij) {
    int i = blockIdx.x * 64 + threadIdx.x;
    int j = blockIdx.y;
    const float* Wp = W + (size_t)i * (JD * UU) + j * (DD * UU);   // 128 contiguous
    float acc = 0.f;
#pragma unroll
    for (int d = 0; d < DD; ++d) {
#pragma unroll
        for (int u = 0; u < UU; ++u) {
            acc += Wp[d * UU + u] * M[(size_t)(j * DD + d) * K1 + u * ISZ + i];
        }
    }
    b_ij[(size_t)j * ISZ + i] += acc * (1.0f / (float)BB);
}

extern "C" void kernel_launch(void* const* d_in, const int* in_sizes, int n_in,
                              void* d_out, int out_size, void* d_ws, size_t ws_size,
                              hipStream_t stream) {
    const float* x = (const float*)d_in[0];   // (256, 8, 1152)
    const float* W = (const float*)d_in[1];   // (1, 1152, 10, 16, 8)
    float* v_out = (float*)d_out;             // (256, 10, 16, 1)

    float* b_ij   = (float*)d_ws;                          // 11,520 f
    float* s_part = b_ij + ISZ * JJ;                       // 16*256*160 = 655,360 f
    float* Mmat   = s_part + (size_t)KS * BB * JD;         // 160*9216 = 1,474,560 f
    unsigned short* xbh = (unsigned short*)(Mmat + (size_t)JD * K1);
    unsigned short* xbl = xbh + (size_t)BB * K1;           // 2,359,296 each
    unsigned short* xth = xbl + (size_t)BB * K1;
    unsigned short* xtl = xth + (size_t)BB * K1;
    unsigned short* bth = xtl + (size_t)BB * K1;           // 160*9216 = 1,474,560 each
    unsigned short* btl = bth + (size_t)JD * K1;
    unsigned short* vth = btl + (size_t)JD * K1;           // 40,960 each
    unsigned short* vtl = vth + (size_t)JD * BB;

    hipLaunchKernelGGL(prep_kernel, dim3(144, 4), dim3(256), 0, stream,
                       x, xbh, xbl, xth, xtl, b_ij);

    for (int it = 0; it < 3; ++it) {
        hipLaunchKernelGGL(build_b_kernel, dim3(JD), dim3(192), 0, stream,
                           W, b_ij, bth, btl, it == 0 ? 1 : 0);
        hipLaunchKernelGGL(sgemm_kernel, dim3(4, 10, KS), dim3(256), 0, stream,
                           xbh, xbl, bth, btl, s_part);
        hipLaunchKernelGGL(reduce_squash_kernel, dim3(BB), dim3(192), 0, stream,
                           s_part, v_out, vth, vtl);
        if (it < 2) {
            hipLaunchKernelGGL(mgemm_kernel, dim3(10, 144), dim3(256), 0, stream,
                               vth, vtl, xth, xtl, Mmat);
            hipLaunchKernelGGL(agree_kernel, dim3(18, 10), dim3(64), 0, stream,
                               W, Mmat, b_ij);
        }
    }
}